// Round 4
// baseline (317.327 us; speedup 1.0000x reference)
//
#include <hip/hip_runtime.h>
#include <math.h>

// ---------------------------------------------------------------------------
// Fused YaRN-GQA attention block, bf16 MFMA pipeline.
// R4: attn restructure — 32 q-rows per wave (Q-tile 128, kt=64): K/V LDS
//     fragment reads shared across two Q-blocks per wave (halves LDS instrs
//     per q-row); Q direct global->regs; no launch_bounds VGPR cap (R3 bug).
//     Keeps: swapped QK^T, ones-MFMA l-sum, defer-max, cvt_pk pack, sigma-V.
// ---------------------------------------------------------------------------

typedef __attribute__((ext_vector_type(8))) short s16x8;
typedef __attribute__((ext_vector_type(4))) float f32x4;
typedef __attribute__((ext_vector_type(4))) unsigned int u32x4;

__device__ __forceinline__ unsigned short f2bf(float x) {
  union { float f; unsigned int u; } v; v.f = x;
  return (unsigned short)((v.u + 0x7FFFu + ((v.u >> 16) & 1u)) >> 16);
}

__device__ __forceinline__ unsigned int cvt_pk_bf16(float lo, float hi) {
  unsigned int r;
  asm("v_cvt_pk_bf16_f32 %0, %1, %2" : "=v"(r) : "v"(lo), "v"(hi));
  return r;
}

#define GLD_LDS16(g, l)                                            \
  __builtin_amdgcn_global_load_lds(                                \
      (const __attribute__((address_space(1))) void*)(g),          \
      (__attribute__((address_space(3))) void*)(l), 16, 0, 0)

// ---------------- cast x (fp32) -> bf16, 4 elems/thread ----------------
__global__ __launch_bounds__(256) void cast_bf16_k(const float* __restrict__ in,
                                                   unsigned short* __restrict__ out) {
  int i = blockIdx.x * 256 + threadIdx.x;
  float4 v = ((const float4*)in)[i];
  unsigned long long pack = (unsigned long long)f2bf(v.x)
                          | ((unsigned long long)f2bf(v.y) << 16)
                          | ((unsigned long long)f2bf(v.z) << 32)
                          | ((unsigned long long)f2bf(v.w) << 48);
  ((unsigned long long*)out)[i] = pack;
}

// ---------------- W (RxC fp32 row-major) -> Wt (CxR bf16) ----------------
__global__ __launch_bounds__(256) void wtrans_k(const float* __restrict__ in,
                                                unsigned short* __restrict__ out,
                                                int R, int C) {
  __shared__ unsigned short lt[64][65];
  const int r0 = blockIdx.x * 64, c0 = blockIdx.y * 64;
  const int j = threadIdx.x & 63, i4 = threadIdx.x >> 6;
#pragma unroll
  for (int p = 0; p < 16; ++p) {
    int i = p * 4 + i4;
    lt[i][j] = f2bf(in[(size_t)(r0 + i) * C + c0 + j]);
  }
  __syncthreads();
#pragma unroll
  for (int p = 0; p < 16; ++p) {
    int i = p * 4 + i4;
    out[(size_t)(c0 + i) * R + r0 + j] = lt[j][i];
  }
}

// ---------------- trig table: cstab[t*64+f] = (cos, sin)(t*invf[f]) ----------
__global__ __launch_bounds__(256) void trig_k(const float* __restrict__ invf,
                                              float2* __restrict__ cstab) {
  int i = blockIdx.x * 256 + threadIdx.x;   // < 2048*64
  int t = i >> 6, f = i & 63;
  float s, c;
  sincosf((float)t * invf[f], &s, &c);
  cstab[i] = make_float2(c, s);
}

// ---------------- GEMM (m97 + XCD swizzle): C = A @ Bt^T, bf16 in, fp32 out --
__global__ __launch_bounds__(256) void gemm_bt_k(const unsigned short* __restrict__ A,
                                                 const unsigned short* __restrict__ Bt,
                                                 float* __restrict__ C,
                                                 int M, int N, int K) {
  __shared__ alignas(16) unsigned short sA[128][32];
  __shared__ alignas(16) unsigned short sB[128][32];
  const int tid = threadIdx.x;
  const int lane = tid & 63;
  const int w = tid >> 6;
  const int wm = (w >> 1) * 64, wn = (w & 1) * 64;
  const int nwg = gridDim.x * gridDim.y;
  int bid = blockIdx.y * gridDim.x + blockIdx.x;
  bid = (bid & 7) * (nwg >> 3) + (bid >> 3);
  const int m0 = (bid % gridDim.x) * 128, n0 = (bid / gridDim.x) * 128;
  const int l15 = lane & 15, kfr = (lane >> 4) * 8;
  f32x4 acc[4][4];
#pragma unroll
  for (int i = 0; i < 4; ++i)
#pragma unroll
    for (int j = 0; j < 4; ++j) acc[i][j] = (f32x4){0.f, 0.f, 0.f, 0.f};
  const int row = tid >> 2, col = (tid & 3) * 8;
  const unsigned short* gA0 = A + (size_t)(m0 + row) * K + col;
  const unsigned short* gA1 = A + (size_t)(m0 + 64 + row) * K + col;
  const unsigned short* gB0 = Bt + (size_t)(n0 + row) * K + col;
  const unsigned short* gB1 = Bt + (size_t)(n0 + 64 + row) * K + col;
  char* ldsA = (char*)&sA[0][0] + w * 1024;
  char* ldsB = (char*)&sB[0][0] + w * 1024;
  for (int k0 = 0; k0 < K; k0 += 32) {
    __syncthreads();
    GLD_LDS16(gA0 + k0, ldsA);
    GLD_LDS16(gA1 + k0, ldsA + 4096);
    GLD_LDS16(gB0 + k0, ldsB);
    GLD_LDS16(gB1 + k0, ldsB + 4096);
    __syncthreads();
    s16x8 af[4], bfr[4];
#pragma unroll
    for (int i = 0; i < 4; ++i) af[i] = *(const s16x8*)&sA[wm + i * 16 + l15][kfr];
#pragma unroll
    for (int j = 0; j < 4; ++j) bfr[j] = *(const s16x8*)&sB[wn + j * 16 + l15][kfr];
#pragma unroll
    for (int i = 0; i < 4; ++i)
#pragma unroll
      for (int j = 0; j < 4; ++j)
        acc[i][j] = __builtin_amdgcn_mfma_f32_16x16x32_bf16(af[i], bfr[j], acc[i][j], 0, 0, 0);
  }
  const int col0 = n0 + wn + l15;
  const int row00 = m0 + wm + (lane >> 4) * 4;
#pragma unroll
  for (int i = 0; i < 4; ++i)
#pragma unroll
    for (int j = 0; j < 4; ++j)
#pragma unroll
      for (int r = 0; r < 4; ++r)
        C[(size_t)(row00 + i * 16 + r) * N + col0 + j * 16] = acc[i][j][r];
}

// ---------------- RMSNorm + RoPE + pack (one wave per 128-vec) ----------------
// qkvf row layout: [0,2048) q heads | [2048,2560) k | [2560,3072) v
__global__ __launch_bounds__(256) void normrope_k(const float* __restrict__ qkvf,
                                                  const float* __restrict__ qw,
                                                  const float* __restrict__ kw,
                                                  const float2* __restrict__ cstab,
                                                  unsigned short* __restrict__ qT,
                                                  unsigned short* __restrict__ kT) {
  constexpr float FOLD =
      (float)(1.4426950408889634 / ((0.1 * 0.6931471805599453 + 1.0) * 11.313708498984761));
  int wid = blockIdx.x * 4 + (threadIdx.x >> 6);
  int lane = threadIdx.x & 63;
  const float* src; const float* wgt; unsigned short* dst;
  int t; float fold;
  if (wid < 65536) {
    int bt = wid >> 4, h = wid & 15;
    int b = bt >> 11; t = bt & 2047;
    src = qkvf + (size_t)bt * 3072 + h * 128;
    wgt = qw;
    dst = qT + ((size_t)(b * 16 + h) * 2048 + t) * 128;
    fold = FOLD;
  } else {
    int id = wid - 65536;
    int bt = id >> 2, g = id & 3;
    int b = bt >> 11; t = bt & 2047;
    src = qkvf + (size_t)bt * 3072 + 2048 + g * 128;
    wgt = kw;
    dst = kT + ((size_t)(b * 4 + g) * 2048 + t) * 128;
    fold = 1.0f;
  }
  float2 v = ((const float2*)src)[lane];
  float ss = v.x * v.x + v.y * v.y;
#pragma unroll
  for (int m = 32; m; m >>= 1) ss += __shfl_xor(ss, m);
  float rs = rsqrtf(ss * (1.0f / 128.0f) + 1.1920929e-07f);
  float2 wv = ((const float2*)wgt)[lane];
  float xn0 = v.x * rs * wv.x;
  float xn1 = v.y * rs * wv.y;
  float px = __shfl_xor(xn0, 32);
  float py = __shfl_xor(xn1, 32);
  float sgn = (lane < 32) ? -1.0f : 1.0f;
  int f0 = (2 * lane) & 63;
  float4 cs = ((const float4*)cstab)[((size_t)t * 64 + f0) >> 1];
  float r0 = (xn0 * cs.x + sgn * px * cs.y) * fold;
  float r1 = (xn1 * cs.z + sgn * py * cs.w) * fold;
  unsigned int packed = (unsigned int)f2bf(r0) | ((unsigned int)f2bf(r1) << 16);
  ((unsigned int*)dst)[lane] = packed;
}

// ---------------- v -> vT[b,g,d,t'] bf16, t' pi-permuted within 32-blocks ----
__global__ __launch_bounds__(256) void vtrans_k(const float* __restrict__ qkvf,
                                                unsigned short* __restrict__ vT) {
  __shared__ unsigned short lt[64][65];
  const int tt0 = blockIdx.x * 64;
  const int dd0 = blockIdx.y * 64;
  const int b = blockIdx.z >> 2, g = blockIdx.z & 3;
  const int j = threadIdx.x & 63, i4 = threadIdx.x >> 6;
  const float* src = qkvf + (size_t)b * 2048 * 3072 + 2560 + g * 128 + dd0;
#pragma unroll
  for (int p = 0; p < 16; ++p) {
    int i = p * 4 + i4;
    lt[i][j] = f2bf(src[(size_t)(tt0 + i) * 3072 + j]);
  }
  __syncthreads();
  unsigned short* dst = vT + ((size_t)(b * 4 + g) * 128 + dd0) * 2048 + tt0;
  const int jp = (j & 32) | (((j & 15) >> 2) << 3) | (((j >> 4) & 1) << 2) | (j & 3);
#pragma unroll
  for (int p = 0; p < 16; ++p) {
    int d = p * 4 + i4;
    dst[(size_t)d * 2048 + jp] = lt[j][d];
  }
}

// ---------------- causal flash attention ----------------
// 4 waves x 32 q-rows (Q-tile 128), kt tiles of 64. Swapped QK^T: lane owns
// q-row l15 of each 16-row sub-block jq in {0,1}; K/V frag reads shared
// across jq. Q direct global->regs. ones-MFMA l-sum; defer-max; cvt_pk pack.
__global__ __launch_bounds__(256) void attn_k(const unsigned short* __restrict__ qT,
                                              const unsigned short* __restrict__ kT,
                                              const unsigned short* __restrict__ vT,
                                              unsigned short* __restrict__ ao) {
  __shared__ alignas(16) unsigned short sK[64][136];
  __shared__ alignas(16) unsigned short sVt[128][72];
  const int tid = threadIdx.x;
  const int lane = tid & 63;
  const int w = tid >> 6;
  const int l15 = lane & 15, lhi = lane >> 4;
  const int qt = 15 - blockIdx.x;          // heavy blocks first
  const int b = blockIdx.y >> 4, h = blockIdx.y & 15, g = h & 3;
  const int q0 = qt * 128;
  const unsigned short* Qb = qT + ((size_t)(b * 16 + h) * 2048) * 128;
  const unsigned short* Kb = kT + ((size_t)(b * 4 + g) * 2048) * 128;
  const unsigned short* Vb = vT + ((size_t)(b * 4 + g) * 128) * 2048;
  const int kr = tid >> 4, kc = (tid & 15) * 8;
  const int vr = tid >> 3, vc = (tid & 7) * 8;

  // Q fragments straight from global (L2): B-frag col=l15 (qrow), k=d slice
  s16x8 qfr[2][4];
#pragma unroll
  for (int jq = 0; jq < 2; ++jq)
#pragma unroll
    for (int ks = 0; ks < 4; ++ks)
      qfr[jq][ks] = *(const s16x8*)(Qb +
          (size_t)(q0 + w * 32 + jq * 16 + l15) * 128 + ks * 32 + lhi * 8);
  // prefetch kt=0 K/V into regs
  u32x4 gk[4], gv[4];
#pragma unroll
  for (int p = 0; p < 4; ++p) {
    gk[p] = *(const u32x4*)(Kb + (size_t)(p * 16 + kr) * 128 + kc);
    gv[p] = *(const u32x4*)(Vb + (size_t)(p * 32 + vr) * 2048 + vc);
  }
  f32x4 o[2][8];
#pragma unroll
  for (int jq = 0; jq < 2; ++jq)
#pragma unroll
    for (int i = 0; i < 8; ++i) o[jq][i] = (f32x4){0.f, 0.f, 0.f, 0.f};
  f32x4 o9[2] = {(f32x4){0.f, 0.f, 0.f, 0.f}, (f32x4){0.f, 0.f, 0.f, 0.f}};
  float m_run[2] = {-INFINITY, -INFINITY};
  s16x8 ones;
#pragma unroll
  for (int j = 0; j < 8; ++j) ones[j] = (short)0x3F80;  // bf16 1.0

  const int ktmax = 2 * qt + 1;
  for (int kt = 0; kt <= ktmax; ++kt) {
    __syncthreads();
#pragma unroll
    for (int p = 0; p < 4; ++p) {
      *(u32x4*)&sK[p * 16 + kr][kc] = gk[p];
      *(u32x4*)&sVt[p * 32 + vr][vc] = gv[p];
    }
    __syncthreads();
    if (kt < ktmax) {                      // T14: issue next-tile loads early
#pragma unroll
      for (int p = 0; p < 4; ++p) {
        gk[p] = *(const u32x4*)(Kb + (size_t)((kt + 1) * 64 + p * 16 + kr) * 128 + kc);
        gv[p] = *(const u32x4*)(Vb + (size_t)(p * 32 + vr) * 2048 + (kt + 1) * 64 + vc);
      }
    }
    // S^T: s[jq][jn][r] = S[qrow = q0+w*32+jq*16+l15][kpos = kt*64+jn*16+lhi*4+r]
    f32x4 s[2][4];
#pragma unroll
    for (int jq = 0; jq < 2; ++jq)
#pragma unroll
      for (int jn = 0; jn < 4; ++jn) s[jq][jn] = (f32x4){0.f, 0.f, 0.f, 0.f};
#pragma unroll
    for (int ks = 0; ks < 4; ++ks)
#pragma unroll
      for (int jn = 0; jn < 4; ++jn) {
        s16x8 ak = *(const s16x8*)&sK[jn * 16 + l15][ks * 32 + lhi * 8];
        s[0][jn] = __builtin_amdgcn_mfma_f32_16x16x32_bf16(ak, qfr[0][ks], s[0][jn], 0, 0, 0);
        s[1][jn] = __builtin_amdgcn_mfma_f32_16x16x32_bf16(ak, qfr[1][ks], s[1][jn], 0, 0, 0);
      }
    if (kt >= 2 * qt) {                    // tiles intersecting the diagonal
#pragma unroll
      for (int jq = 0; jq < 2; ++jq)
#pragma unroll
        for (int jn = 0; jn < 4; ++jn)
#pragma unroll
          for (int r = 0; r < 4; ++r)
            if (kt * 64 + jn * 16 + lhi * 4 + r > q0 + w * 32 + jq * 16 + l15)
              s[jq][jn][r] = -INFINITY;
    }
    // row max per jq (per-lane row) + reduce across the 4 lhi copies
    float mx[2];
#pragma unroll
    for (int jq = 0; jq < 2; ++jq) {
      float m = fmaxf(fmaxf(fmaxf(s[jq][0][0], s[jq][0][1]), fmaxf(s[jq][0][2], s[jq][0][3])),
                      fmaxf(fmaxf(s[jq][1][0], s[jq][1][1]), fmaxf(s[jq][1][2], s[jq][1][3])));
      m = fmaxf(m, fmaxf(fmaxf(fmaxf(s[jq][2][0], s[jq][2][1]), fmaxf(s[jq][2][2], s[jq][2][3])),
                         fmaxf(fmaxf(s[jq][3][0], s[jq][3][1]), fmaxf(s[jq][3][2], s[jq][3][3]))));
      m = fmaxf(m, __shfl_xor(m, 16));
      m = fmaxf(m, __shfl_xor(m, 32));
      mx[jq] = m;
    }
    // T13 defer-max: rescale only when a max grew past threshold (exp2 units)
    if (!__all(fmaxf(mx[0] - m_run[0], mx[1] - m_run[1]) <= 8.0f)) {
#pragma unroll
      for (int jq = 0; jq < 2; ++jq) {
        float mnew = fmaxf(m_run[jq], mx[jq]);
        float scale = exp2f(m_run[jq] - mnew);
        m_run[jq] = mnew;
        float sc_o[4];
#pragma unroll
        for (int r = 0; r < 4; ++r) sc_o[r] = __shfl(scale, lhi * 4 + r);
#pragma unroll
        for (int nt = 0; nt < 8; ++nt)
#pragma unroll
          for (int r = 0; r < 4; ++r) o[jq][nt][r] *= sc_o[r];
#pragma unroll
        for (int r = 0; r < 4; ++r) o9[jq][r] *= sc_o[r];
      }
    }
    // P = exp2(S - m); pack to bf16 A-frags via cvt_pk; l-sum via ones-MFMA
    union { s16x8 v; unsigned int d[4]; } pa[2][2];
#pragma unroll
    for (int jq = 0; jq < 2; ++jq) {
      float pp[4][4];
#pragma unroll
      for (int jn = 0; jn < 4; ++jn)
#pragma unroll
        for (int r = 0; r < 4; ++r) pp[jn][r] = exp2f(s[jq][jn][r] - m_run[jq]);
#pragma unroll
      for (int d = 0; d < 2; ++d) {
        pa[jq][0].d[d]     = cvt_pk_bf16(pp[0][2 * d], pp[0][2 * d + 1]);
        pa[jq][0].d[2 + d] = cvt_pk_bf16(pp[1][2 * d], pp[1][2 * d + 1]);
        pa[jq][1].d[d]     = cvt_pk_bf16(pp[2][2 * d], pp[2][2 * d + 1]);
        pa[jq][1].d[2 + d] = cvt_pk_bf16(pp[3][2 * d], pp[3][2 * d + 1]);
      }
      o9[jq] = __builtin_amdgcn_mfma_f32_16x16x32_bf16(pa[jq][0].v, ones, o9[jq], 0, 0, 0);
      o9[jq] = __builtin_amdgcn_mfma_f32_16x16x32_bf16(pa[jq][1].v, ones, o9[jq], 0, 0, 0);
    }
    // O += P V  (V frag reads shared across jq)
#pragma unroll
    for (int nt = 0; nt < 8; ++nt) {
      s16x8 vb0 = *(const s16x8*)&sVt[nt * 16 + l15][lhi * 8];
      o[0][nt] = __builtin_amdgcn_mfma_f32_16x16x32_bf16(pa[0][0].v, vb0, o[0][nt], 0, 0, 0);
      o[1][nt] = __builtin_amdgcn_mfma_f32_16x16x32_bf16(pa[1][0].v, vb0, o[1][nt], 0, 0, 0);
    }
#pragma unroll
    for (int nt = 0; nt < 8; ++nt) {
      s16x8 vb1 = *(const s16x8*)&sVt[nt * 16 + l15][32 + lhi * 8];
      o[0][nt] = __builtin_amdgcn_mfma_f32_16x16x32_bf16(pa[0][1].v, vb1, o[0][nt], 0, 0, 0);
      o[1][nt] = __builtin_amdgcn_mfma_f32_16x16x32_bf16(pa[1][1].v, vb1, o[1][nt], 0, 0, 0);
    }
  }
  // epilogue: o9[jq][r] is the row-sum for row lhi*4+r of sub-block jq
#pragma unroll
  for (int jq = 0; jq < 2; ++jq)
#pragma unroll
    for (int r = 0; r < 4; ++r) {
      float invr = 1.0f / o9[jq][r];
      int t = q0 + w * 32 + jq * 16 + lhi * 4 + r;
      size_t base = ((size_t)b * 2048 + t) * 2048 + h * 128;
#pragma unroll
      for (int nt = 0; nt < 8; ++nt)
        ao[base + nt * 16 + l15] = f2bf(o[jq][nt][r] * invr);
    }
}

// ---------------------------------------------------------------------------
extern "C" void kernel_launch(void* const* d_in, const int* in_sizes, int n_in,
                              void* d_out, int out_size, void* d_ws, size_t ws_size,
                              hipStream_t stream) {
  (void)in_sizes; (void)n_in; (void)out_size; (void)ws_size;
  const float* x    = (const float*)d_in[0];
  const float* Wq   = (const float*)d_in[1];
  const float* Wkv  = (const float*)d_in[2];
  const float* Wout = (const float*)d_in[3];
  const float* qw   = (const float*)d_in[4];
  const float* kw   = (const float*)d_in[5];
  const float* invf = (const float*)d_in[6];
  float* out = (float*)d_out;

  char* ws = (char*)d_ws;
  size_t off = 0;
  auto alloc = [&](size_t bytes) -> void* {
    void* p = ws + off; off += (bytes + 255) & ~(size_t)255; return p;
  };
  unsigned short* xb    = (unsigned short*)alloc((size_t)4096 * 2048 * 2);
  unsigned short* wqkvt = (unsigned short*)alloc((size_t)3072 * 2048 * 2);
  unsigned short* wot   = (unsigned short*)alloc((size_t)2048 * 2048 * 2);
  float* qkvf = (float*)alloc((size_t)4096 * 3072 * 4);
  float2* cstab = (float2*)alloc((size_t)2048 * 64 * 8);
  unsigned short* qT = (unsigned short*)alloc((size_t)2 * 16 * 2048 * 128 * 2);
  unsigned short* kT = (unsigned short*)alloc((size_t)2 * 4 * 2048 * 128 * 2);
  unsigned short* vT = (unsigned short*)alloc((size_t)2 * 4 * 128 * 2048 * 2);
  unsigned short* ao = (unsigned short*)alloc((size_t)4096 * 2048 * 2);

  cast_bf16_k<<<8192, 256, 0, stream>>>(x, xb);
  wtrans_k<<<dim3(32, 32), 256, 0, stream>>>(Wq, wqkvt, 2048, 2048);
  wtrans_k<<<dim3(32, 16), 256, 0, stream>>>(Wkv, wqkvt + (size_t)2048 * 2048, 2048, 1024);
  wtrans_k<<<dim3(32, 32), 256, 0, stream>>>(Wout, wot, 2048, 2048);
  trig_k<<<512, 256, 0, stream>>>(invf, cstab);
  gemm_bt_k<<<dim3(32, 24), 256, 0, stream>>>(xb, wqkvt, qkvf, 4096, 3072, 2048);
  normrope_k<<<20480, 256, 0, stream>>>(qkvf, qw, kw, cstab, qT, kT);
  vtrans_k<<<dim3(32, 2, 8), 256, 0, stream>>>(qkvf, vT);
  attn_k<<<dim3(16, 32), 256, 0, stream>>>(qT, kT, vT, ao);
  gemm_bt_k<<<dim3(32, 16), 256, 0, stream>>>(ao, wot, out, 4096, 2048, 2048);
}

// Round 5
// 270.900 us; speedup vs baseline: 1.1714x; 1.1714x over previous
//
#include <hip/hip_runtime.h>
#include <math.h>

// ---------------------------------------------------------------------------
// Fused YaRN-GQA attention block, bf16 MFMA pipeline.
// R5: attn scheduling fix — 1D grid with (a) work-paired qt mapping so each
//     co-resident block pair (bid, bid+256) does exactly 36 iters, and
//     (b) XCD-pinned columns (bid%8 == b*4+g) so each KV group lives in one
//     XCD's L2 (3MB working set < 4MB). Kernel body identical to R4.
// ---------------------------------------------------------------------------

typedef __attribute__((ext_vector_type(8))) short s16x8;
typedef __attribute__((ext_vector_type(4))) float f32x4;
typedef __attribute__((ext_vector_type(4))) unsigned int u32x4;

__device__ __forceinline__ unsigned short f2bf(float x) {
  union { float f; unsigned int u; } v; v.f = x;
  return (unsigned short)((v.u + 0x7FFFu + ((v.u >> 16) & 1u)) >> 16);
}

__device__ __forceinline__ unsigned int cvt_pk_bf16(float lo, float hi) {
  unsigned int r;
  asm("v_cvt_pk_bf16_f32 %0, %1, %2" : "=v"(r) : "v"(lo), "v"(hi));
  return r;
}

#define GLD_LDS16(g, l)                                            \
  __builtin_amdgcn_global_load_lds(                                \
      (const __attribute__((address_space(1))) void*)(g),          \
      (__attribute__((address_space(3))) void*)(l), 16, 0, 0)

// ---------------- cast x (fp32) -> bf16, 4 elems/thread ----------------
__global__ __launch_bounds__(256) void cast_bf16_k(const float* __restrict__ in,
                                                   unsigned short* __restrict__ out) {
  int i = blockIdx.x * 256 + threadIdx.x;
  float4 v = ((const float4*)in)[i];
  unsigned long long pack = (unsigned long long)f2bf(v.x)
                          | ((unsigned long long)f2bf(v.y) << 16)
                          | ((unsigned long long)f2bf(v.z) << 32)
                          | ((unsigned long long)f2bf(v.w) << 48);
  ((unsigned long long*)out)[i] = pack;
}

// ---------------- W (RxC fp32 row-major) -> Wt (CxR bf16) ----------------
__global__ __launch_bounds__(256) void wtrans_k(const float* __restrict__ in,
                                                unsigned short* __restrict__ out,
                                                int R, int C) {
  __shared__ unsigned short lt[64][65];
  const int r0 = blockIdx.x * 64, c0 = blockIdx.y * 64;
  const int j = threadIdx.x & 63, i4 = threadIdx.x >> 6;
#pragma unroll
  for (int p = 0; p < 16; ++p) {
    int i = p * 4 + i4;
    lt[i][j] = f2bf(in[(size_t)(r0 + i) * C + c0 + j]);
  }
  __syncthreads();
#pragma unroll
  for (int p = 0; p < 16; ++p) {
    int i = p * 4 + i4;
    out[(size_t)(c0 + i) * R + r0 + j] = lt[j][i];
  }
}

// ---------------- trig table: cstab[t*64+f] = (cos, sin)(t*invf[f]) ----------
__global__ __launch_bounds__(256) void trig_k(const float* __restrict__ invf,
                                              float2* __restrict__ cstab) {
  int i = blockIdx.x * 256 + threadIdx.x;   // < 2048*64
  int t = i >> 6, f = i & 63;
  float s, c;
  sincosf((float)t * invf[f], &s, &c);
  cstab[i] = make_float2(c, s);
}

// ---------------- GEMM (m97 + XCD swizzle): C = A @ Bt^T, bf16 in, fp32 out --
__global__ __launch_bounds__(256) void gemm_bt_k(const unsigned short* __restrict__ A,
                                                 const unsigned short* __restrict__ Bt,
                                                 float* __restrict__ C,
                                                 int M, int N, int K) {
  __shared__ alignas(16) unsigned short sA[128][32];
  __shared__ alignas(16) unsigned short sB[128][32];
  const int tid = threadIdx.x;
  const int lane = tid & 63;
  const int w = tid >> 6;
  const int wm = (w >> 1) * 64, wn = (w & 1) * 64;
  const int nwg = gridDim.x * gridDim.y;
  int bid = blockIdx.y * gridDim.x + blockIdx.x;
  bid = (bid & 7) * (nwg >> 3) + (bid >> 3);
  const int m0 = (bid % gridDim.x) * 128, n0 = (bid / gridDim.x) * 128;
  const int l15 = lane & 15, kfr = (lane >> 4) * 8;
  f32x4 acc[4][4];
#pragma unroll
  for (int i = 0; i < 4; ++i)
#pragma unroll
    for (int j = 0; j < 4; ++j) acc[i][j] = (f32x4){0.f, 0.f, 0.f, 0.f};
  const int row = tid >> 2, col = (tid & 3) * 8;
  const unsigned short* gA0 = A + (size_t)(m0 + row) * K + col;
  const unsigned short* gA1 = A + (size_t)(m0 + 64 + row) * K + col;
  const unsigned short* gB0 = Bt + (size_t)(n0 + row) * K + col;
  const unsigned short* gB1 = Bt + (size_t)(n0 + 64 + row) * K + col;
  char* ldsA = (char*)&sA[0][0] + w * 1024;
  char* ldsB = (char*)&sB[0][0] + w * 1024;
  for (int k0 = 0; k0 < K; k0 += 32) {
    __syncthreads();
    GLD_LDS16(gA0 + k0, ldsA);
    GLD_LDS16(gA1 + k0, ldsA + 4096);
    GLD_LDS16(gB0 + k0, ldsB);
    GLD_LDS16(gB1 + k0, ldsB + 4096);
    __syncthreads();
    s16x8 af[4], bfr[4];
#pragma unroll
    for (int i = 0; i < 4; ++i) af[i] = *(const s16x8*)&sA[wm + i * 16 + l15][kfr];
#pragma unroll
    for (int j = 0; j < 4; ++j) bfr[j] = *(const s16x8*)&sB[wn + j * 16 + l15][kfr];
#pragma unroll
    for (int i = 0; i < 4; ++i)
#pragma unroll
      for (int j = 0; j < 4; ++j)
        acc[i][j] = __builtin_amdgcn_mfma_f32_16x16x32_bf16(af[i], bfr[j], acc[i][j], 0, 0, 0);
  }
  const int col0 = n0 + wn + l15;
  const int row00 = m0 + wm + (lane >> 4) * 4;
#pragma unroll
  for (int i = 0; i < 4; ++i)
#pragma unroll
    for (int j = 0; j < 4; ++j)
#pragma unroll
      for (int r = 0; r < 4; ++r)
        C[(size_t)(row00 + i * 16 + r) * N + col0 + j * 16] = acc[i][j][r];
}

// ---------------- RMSNorm + RoPE + pack (one wave per 128-vec) ----------------
// qkvf row layout: [0,2048) q heads | [2048,2560) k | [2560,3072) v
__global__ __launch_bounds__(256) void normrope_k(const float* __restrict__ qkvf,
                                                  const float* __restrict__ qw,
                                                  const float* __restrict__ kw,
                                                  const float2* __restrict__ cstab,
                                                  unsigned short* __restrict__ qT,
                                                  unsigned short* __restrict__ kT) {
  constexpr float FOLD =
      (float)(1.4426950408889634 / ((0.1 * 0.6931471805599453 + 1.0) * 11.313708498984761));
  int wid = blockIdx.x * 4 + (threadIdx.x >> 6);
  int lane = threadIdx.x & 63;
  const float* src; const float* wgt; unsigned short* dst;
  int t; float fold;
  if (wid < 65536) {
    int bt = wid >> 4, h = wid & 15;
    int b = bt >> 11; t = bt & 2047;
    src = qkvf + (size_t)bt * 3072 + h * 128;
    wgt = qw;
    dst = qT + ((size_t)(b * 16 + h) * 2048 + t) * 128;
    fold = FOLD;
  } else {
    int id = wid - 65536;
    int bt = id >> 2, g = id & 3;
    int b = bt >> 11; t = bt & 2047;
    src = qkvf + (size_t)bt * 3072 + 2048 + g * 128;
    wgt = kw;
    dst = kT + ((size_t)(b * 4 + g) * 2048 + t) * 128;
    fold = 1.0f;
  }
  float2 v = ((const float2*)src)[lane];
  float ss = v.x * v.x + v.y * v.y;
#pragma unroll
  for (int m = 32; m; m >>= 1) ss += __shfl_xor(ss, m);
  float rs = rsqrtf(ss * (1.0f / 128.0f) + 1.1920929e-07f);
  float2 wv = ((const float2*)wgt)[lane];
  float xn0 = v.x * rs * wv.x;
  float xn1 = v.y * rs * wv.y;
  float px = __shfl_xor(xn0, 32);
  float py = __shfl_xor(xn1, 32);
  float sgn = (lane < 32) ? -1.0f : 1.0f;
  int f0 = (2 * lane) & 63;
  float4 cs = ((const float4*)cstab)[((size_t)t * 64 + f0) >> 1];
  float r0 = (xn0 * cs.x + sgn * px * cs.y) * fold;
  float r1 = (xn1 * cs.z + sgn * py * cs.w) * fold;
  unsigned int packed = (unsigned int)f2bf(r0) | ((unsigned int)f2bf(r1) << 16);
  ((unsigned int*)dst)[lane] = packed;
}

// ---------------- v -> vT[b,g,d,t'] bf16, t' pi-permuted within 32-blocks ----
__global__ __launch_bounds__(256) void vtrans_k(const float* __restrict__ qkvf,
                                                unsigned short* __restrict__ vT) {
  __shared__ unsigned short lt[64][65];
  const int tt0 = blockIdx.x * 64;
  const int dd0 = blockIdx.y * 64;
  const int b = blockIdx.z >> 2, g = blockIdx.z & 3;
  const int j = threadIdx.x & 63, i4 = threadIdx.x >> 6;
  const float* src = qkvf + (size_t)b * 2048 * 3072 + 2560 + g * 128 + dd0;
#pragma unroll
  for (int p = 0; p < 16; ++p) {
    int i = p * 4 + i4;
    lt[i][j] = f2bf(src[(size_t)(tt0 + i) * 3072 + j]);
  }
  __syncthreads();
  unsigned short* dst = vT + ((size_t)(b * 4 + g) * 128 + dd0) * 2048 + tt0;
  const int jp = (j & 32) | (((j & 15) >> 2) << 3) | (((j >> 4) & 1) << 2) | (j & 3);
#pragma unroll
  for (int p = 0; p < 16; ++p) {
    int d = p * 4 + i4;
    dst[(size_t)d * 2048 + jp] = lt[j][d];
  }
}

// ---------------- causal flash attention ----------------
// 4 waves x 32 q-rows (Q-tile 128), kt tiles of 64. Swapped QK^T; K/V frag
// reads shared across jq; Q direct global->regs; ones-MFMA l-sum; defer-max;
// cvt_pk pack. R5: 1D grid, work-paired qt mapping + XCD-pinned columns:
//   bid%8 = b*4+g (KV group per XCD); pair (bid, bid+256) does 36 iters total.
__global__ __launch_bounds__(256) void attn_k(const unsigned short* __restrict__ qT,
                                              const unsigned short* __restrict__ kT,
                                              const unsigned short* __restrict__ vT,
                                              unsigned short* __restrict__ ao) {
  __shared__ alignas(16) unsigned short sK[64][136];
  __shared__ alignas(16) unsigned short sVt[128][72];
  const int tid = threadIdx.x;
  const int lane = tid & 63;
  const int w = tid >> 6;
  const int l15 = lane & 15, lhi = lane >> 4;
  // --- R5 mapping ---
  const int bid = blockIdx.x;              // 0..511
  const int u = bid & 255, hi = bid >> 8;
  const int colc = u & 31;                 // column code: (h>>2)*8 + b*4 + g
  const int jj = u >> 5;                   // 0..7
  const int qt = hi ? jj : 15 - jj;        // pair (bid,bid+256): 36 iters total
  const int b = (colc >> 2) & 1, g = colc & 3;
  const int h = (colc >> 3) * 4 + g;
  const int q0 = qt * 128;
  const unsigned short* Qb = qT + ((size_t)(b * 16 + h) * 2048) * 128;
  const unsigned short* Kb = kT + ((size_t)(b * 4 + g) * 2048) * 128;
  const unsigned short* Vb = vT + ((size_t)(b * 4 + g) * 128) * 2048;
  const int kr = tid >> 4, kc = (tid & 15) * 8;
  const int vr = tid >> 3, vc = (tid & 7) * 8;

  // Q fragments straight from global (L2): B-frag col=l15 (qrow), k=d slice
  s16x8 qfr[2][4];
#pragma unroll
  for (int jq = 0; jq < 2; ++jq)
#pragma unroll
    for (int ks = 0; ks < 4; ++ks)
      qfr[jq][ks] = *(const s16x8*)(Qb +
          (size_t)(q0 + w * 32 + jq * 16 + l15) * 128 + ks * 32 + lhi * 8);
  // prefetch kt=0 K/V into regs
  u32x4 gk[4], gv[4];
#pragma unroll
  for (int p = 0; p < 4; ++p) {
    gk[p] = *(const u32x4*)(Kb + (size_t)(p * 16 + kr) * 128 + kc);
    gv[p] = *(const u32x4*)(Vb + (size_t)(p * 32 + vr) * 2048 + vc);
  }
  f32x4 o[2][8];
#pragma unroll
  for (int jq = 0; jq < 2; ++jq)
#pragma unroll
    for (int i = 0; i < 8; ++i) o[jq][i] = (f32x4){0.f, 0.f, 0.f, 0.f};
  f32x4 o9[2] = {(f32x4){0.f, 0.f, 0.f, 0.f}, (f32x4){0.f, 0.f, 0.f, 0.f}};
  float m_run[2] = {-INFINITY, -INFINITY};
  s16x8 ones;
#pragma unroll
  for (int j = 0; j < 8; ++j) ones[j] = (short)0x3F80;  // bf16 1.0

  const int ktmax = 2 * qt + 1;
  for (int kt = 0; kt <= ktmax; ++kt) {
    __syncthreads();
#pragma unroll
    for (int p = 0; p < 4; ++p) {
      *(u32x4*)&sK[p * 16 + kr][kc] = gk[p];
      *(u32x4*)&sVt[p * 32 + vr][vc] = gv[p];
    }
    __syncthreads();
    if (kt < ktmax) {                      // T14: issue next-tile loads early
#pragma unroll
      for (int p = 0; p < 4; ++p) {
        gk[p] = *(const u32x4*)(Kb + (size_t)((kt + 1) * 64 + p * 16 + kr) * 128 + kc);
        gv[p] = *(const u32x4*)(Vb + (size_t)(p * 32 + vr) * 2048 + (kt + 1) * 64 + vc);
      }
    }
    // S^T: s[jq][jn][r] = S[qrow = q0+w*32+jq*16+l15][kpos = kt*64+jn*16+lhi*4+r]
    f32x4 s[2][4];
#pragma unroll
    for (int jq = 0; jq < 2; ++jq)
#pragma unroll
      for (int jn = 0; jn < 4; ++jn) s[jq][jn] = (f32x4){0.f, 0.f, 0.f, 0.f};
#pragma unroll
    for (int ks = 0; ks < 4; ++ks)
#pragma unroll
      for (int jn = 0; jn < 4; ++jn) {
        s16x8 ak = *(const s16x8*)&sK[jn * 16 + l15][ks * 32 + lhi * 8];
        s[0][jn] = __builtin_amdgcn_mfma_f32_16x16x32_bf16(ak, qfr[0][ks], s[0][jn], 0, 0, 0);
        s[1][jn] = __builtin_amdgcn_mfma_f32_16x16x32_bf16(ak, qfr[1][ks], s[1][jn], 0, 0, 0);
      }
    if (kt >= 2 * qt) {                    // tiles intersecting the diagonal
#pragma unroll
      for (int jq = 0; jq < 2; ++jq)
#pragma unroll
        for (int jn = 0; jn < 4; ++jn)
#pragma unroll
          for (int r = 0; r < 4; ++r)
            if (kt * 64 + jn * 16 + lhi * 4 + r > q0 + w * 32 + jq * 16 + l15)
              s[jq][jn][r] = -INFINITY;
    }
    // row max per jq (per-lane row) + reduce across the 4 lhi copies
    float mx[2];
#pragma unroll
    for (int jq = 0; jq < 2; ++jq) {
      float m = fmaxf(fmaxf(fmaxf(s[jq][0][0], s[jq][0][1]), fmaxf(s[jq][0][2], s[jq][0][3])),
                      fmaxf(fmaxf(s[jq][1][0], s[jq][1][1]), fmaxf(s[jq][1][2], s[jq][1][3])));
      m = fmaxf(m, fmaxf(fmaxf(fmaxf(s[jq][2][0], s[jq][2][1]), fmaxf(s[jq][2][2], s[jq][2][3])),
                         fmaxf(fmaxf(s[jq][3][0], s[jq][3][1]), fmaxf(s[jq][3][2], s[jq][3][3]))));
      m = fmaxf(m, __shfl_xor(m, 16));
      m = fmaxf(m, __shfl_xor(m, 32));
      mx[jq] = m;
    }
    // T13 defer-max: rescale only when a max grew past threshold (exp2 units)
    if (!__all(fmaxf(mx[0] - m_run[0], mx[1] - m_run[1]) <= 8.0f)) {
#pragma unroll
      for (int jq = 0; jq < 2; ++jq) {
        float mnew = fmaxf(m_run[jq], mx[jq]);
        float scale = exp2f(m_run[jq] - mnew);
        m_run[jq] = mnew;
        float sc_o[4];
#pragma unroll
        for (int r = 0; r < 4; ++r) sc_o[r] = __shfl(scale, lhi * 4 + r);
#pragma unroll
        for (int nt = 0; nt < 8; ++nt)
#pragma unroll
          for (int r = 0; r < 4; ++r) o[jq][nt][r] *= sc_o[r];
#pragma unroll
        for (int r = 0; r < 4; ++r) o9[jq][r] *= sc_o[r];
      }
    }
    // P = exp2(S - m); pack to bf16 A-frags via cvt_pk; l-sum via ones-MFMA
    union { s16x8 v; unsigned int d[4]; } pa[2][2];
#pragma unroll
    for (int jq = 0; jq < 2; ++jq) {
      float pp[4][4];
#pragma unroll
      for (int jn = 0; jn < 4; ++jn)
#pragma unroll
        for (int r = 0; r < 4; ++r) pp[jn][r] = exp2f(s[jq][jn][r] - m_run[jq]);
#pragma unroll
      for (int d = 0; d < 2; ++d) {
        pa[jq][0].d[d]     = cvt_pk_bf16(pp[0][2 * d], pp[0][2 * d + 1]);
        pa[jq][0].d[2 + d] = cvt_pk_bf16(pp[1][2 * d], pp[1][2 * d + 1]);
        pa[jq][1].d[d]     = cvt_pk_bf16(pp[2][2 * d], pp[2][2 * d + 1]);
        pa[jq][1].d[2 + d] = cvt_pk_bf16(pp[3][2 * d], pp[3][2 * d + 1]);
      }
      o9[jq] = __builtin_amdgcn_mfma_f32_16x16x32_bf16(pa[jq][0].v, ones, o9[jq], 0, 0, 0);
      o9[jq] = __builtin_amdgcn_mfma_f32_16x16x32_bf16(pa[jq][1].v, ones, o9[jq], 0, 0, 0);
    }
    // O += P V  (V frag reads shared across jq)
#pragma unroll
    for (int nt = 0; nt < 8; ++nt) {
      s16x8 vb0 = *(const s16x8*)&sVt[nt * 16 + l15][lhi * 8];
      o[0][nt] = __builtin_amdgcn_mfma_f32_16x16x32_bf16(pa[0][0].v, vb0, o[0][nt], 0, 0, 0);
      o[1][nt] = __builtin_amdgcn_mfma_f32_16x16x32_bf16(pa[1][0].v, vb0, o[1][nt], 0, 0, 0);
    }
#pragma unroll
    for (int nt = 0; nt < 8; ++nt) {
      s16x8 vb1 = *(const s16x8*)&sVt[nt * 16 + l15][32 + lhi * 8];
      o[0][nt] = __builtin_amdgcn_mfma_f32_16x16x32_bf16(pa[0][1].v, vb1, o[0][nt], 0, 0, 0);
      o[1][nt] = __builtin_amdgcn_mfma_f32_16x16x32_bf16(pa[1][1].v, vb1, o[1][nt], 0, 0, 0);
    }
  }
  // epilogue: o9[jq][r] is the row-sum for row lhi*4+r of sub-block jq
#pragma unroll
  for (int jq = 0; jq < 2; ++jq)
#pragma unroll
    for (int r = 0; r < 4; ++r) {
      float invr = 1.0f / o9[jq][r];
      int t = q0 + w * 32 + jq * 16 + lhi * 4 + r;
      size_t base = ((size_t)b * 2048 + t) * 2048 + h * 128;
#pragma unroll
      for (int nt = 0; nt < 8; ++nt)
        ao[base + nt * 16 + l15] = f2bf(o[jq][nt][r] * invr);
    }
}

// ---------------------------------------------------------------------------
extern "C" void kernel_launch(void* const* d_in, const int* in_sizes, int n_in,
                              void* d_out, int out_size, void* d_ws, size_t ws_size,
                              hipStream_t stream) {
  (void)in_sizes; (void)n_in; (void)out_size; (void)ws_size;
  const float* x    = (const float*)d_in[0];
  const float* Wq   = (const float*)d_in[1];
  const float* Wkv  = (const float*)d_in[2];
  const float* Wout = (const float*)d_in[3];
  const float* qw   = (const float*)d_in[4];
  const float* kw   = (const float*)d_in[5];
  const float* invf = (const float*)d_in[6];
  float* out = (float*)d_out;

  char* ws = (char*)d_ws;
  size_t off = 0;
  auto alloc = [&](size_t bytes) -> void* {
    void* p = ws + off; off += (bytes + 255) & ~(size_t)255; return p;
  };
  unsigned short* xb    = (unsigned short*)alloc((size_t)4096 * 2048 * 2);
  unsigned short* wqkvt = (unsigned short*)alloc((size_t)3072 * 2048 * 2);
  unsigned short* wot   = (unsigned short*)alloc((size_t)2048 * 2048 * 2);
  float* qkvf = (float*)alloc((size_t)4096 * 3072 * 4);
  float2* cstab = (float2*)alloc((size_t)2048 * 64 * 8);
  unsigned short* qT = (unsigned short*)alloc((size_t)2 * 16 * 2048 * 128 * 2);
  unsigned short* kT = (unsigned short*)alloc((size_t)2 * 4 * 2048 * 128 * 2);
  unsigned short* vT = (unsigned short*)alloc((size_t)2 * 4 * 128 * 2048 * 2);
  unsigned short* ao = (unsigned short*)alloc((size_t)4096 * 2048 * 2);

  cast_bf16_k<<<8192, 256, 0, stream>>>(x, xb);
  wtrans_k<<<dim3(32, 32), 256, 0, stream>>>(Wq, wqkvt, 2048, 2048);
  wtrans_k<<<dim3(32, 16), 256, 0, stream>>>(Wkv, wqkvt + (size_t)2048 * 2048, 2048, 1024);
  wtrans_k<<<dim3(32, 32), 256, 0, stream>>>(Wout, wot, 2048, 2048);
  trig_k<<<512, 256, 0, stream>>>(invf, cstab);
  gemm_bt_k<<<dim3(32, 24), 256, 0, stream>>>(xb, wqkvt, qkvf, 4096, 3072, 2048);
  normrope_k<<<20480, 256, 0, stream>>>(qkvf, qw, kw, cstab, qT, kT);
  vtrans_k<<<dim3(32, 2, 8), 256, 0, stream>>>(qkvf, vT);
  attn_k<<<512, 256, 0, stream>>>(qT, kT, vT, ao);
  gemm_bt_k<<<dim3(32, 16), 256, 0, stream>>>(ao, wot, out, 4096, 2048, 2048);
}